// Round 1
// baseline (224.409 us; speedup 1.0000x reference)
//
#include <hip/hip_runtime.h>

#define LL 8192
#define HH 128

typedef __attribute__((ext_vector_type(8))) short short8v;
typedef __attribute__((ext_vector_type(4))) short short4v;
typedef __attribute__((ext_vector_type(4))) float f32x4;

__device__ inline short f2bf(float f) {
    union { float f; unsigned u; } x; x.f = f;
    unsigned r = (x.u + 0x7fffu + ((x.u >> 16) & 1u)) >> 16;
    return (short)r;
}
__device__ inline float bf2f(short s) {
    union { unsigned u; float f; } x; x.u = ((unsigned)(unsigned short)s) << 16;
    return x.f;
}

// Swizzled sA pointer: rows of 128 shorts (256 B, no pad). Row stride 256 B is
// 0 mod 128 B of bank space, so unswizzled the 16 l15-lanes of a b128 read all
// hit the same 16B bank window (~16-way conflict, 2.78M conflict cycles
// measured). XOR bits 4-6 with row&7 spreads each 8-row stripe across all 8
// 16B windows -> hits the 8-access/bank floor for a 1KB wave read.
// All sA traffic is 16B-granular so the swizzle is safe on both sides.
__device__ inline short* sAp(short* base, int row, int col) {
    int byte = (row << 8) + (col << 1);
    byte ^= (row & 7) << 4;
    return (short*)((char*)base + byte);
}

// LN of 4 rows per wave (row = base + quad), 8 consecutive floats per l15 lane.
// 4-level shfl_xor chain within 16-lane groups (offsets <16 never cross the
// group) instead of the old 6-level/64-lane chain at 2 elems/lane: 1/4 the
// dependent DS ops, 4 independent rows in flight per wave.
__device__ inline short8v ln_pack8(const float* rowF, int l15) {
    const float4 a = *(const float4*)&rowF[l15 * 8];
    const float4 b = *(const float4*)&rowF[l15 * 8 + 4];
    float s  = (a.x + a.y) + (a.z + a.w) + (b.x + b.y) + (b.z + b.w);
    float s2 = a.x * a.x + a.y * a.y + a.z * a.z + a.w * a.w
             + b.x * b.x + b.y * b.y + b.z * b.z + b.w * b.w;
#pragma unroll
    for (int off = 1; off <= 8; off <<= 1) {
        s  += __shfl_xor(s,  off, 64);
        s2 += __shfl_xor(s2, off, 64);
    }
    float mu = s * (1.f / 128.f);
    float var = s2 * (1.f / 128.f) - mu * mu;
    float rstd = rsqrtf(var + 1e-5f);
    short8v r;
    r[0] = f2bf((a.x - mu) * rstd);
    r[1] = f2bf((a.y - mu) * rstd);
    r[2] = f2bf((a.z - mu) * rstd);
    r[3] = f2bf((a.w - mu) * rstd);
    r[4] = f2bf((b.x - mu) * rstd);
    r[5] = f2bf((b.y - mu) * rstd);
    r[6] = f2bf((b.z - mu) * rstd);
    r[7] = f2bf((b.w - mu) * rstd);
    return r;
}

// ---------------------------------------------------------------------------
// one repack kernel: conv w -> bf16 [lay][k][o][i]; Wq/Wk/Wv stacked bf16
// (q-scale folded); b3; Wff bf16; AND h0 = x + pos_encoding (fp32 table).
// PE hoisted here: computed ONCE per element (vs 3x per element inside the
// halo'd conv kernel) with the identical powf/sinf/cosf math -> no numerics
// drift, and the ~10K-VALU-inst/thread transcendental cost leaves the
// latency-critical conv kernel.
// ---------------------------------------------------------------------------
__global__ __launch_bounds__(256) void repack_all(const float* __restrict__ x,
                                                  const float* __restrict__ w,
                                                  const float* __restrict__ Wq,
                                                  const float* __restrict__ Wk,
                                                  const float* __restrict__ Wv,
                                                  const float* __restrict__ bq,
                                                  const float* __restrict__ bk,
                                                  const float* __restrict__ bv,
                                                  const float* __restrict__ Wff,
                                                  short* __restrict__ wkb,
                                                  short* __restrict__ wqkvb,
                                                  float* __restrict__ b3,
                                                  short* __restrict__ wffb,
                                                  float* __restrict__ h0) {
    const float qs = 0.08838834764831845f;
    int idx = blockIdx.x * 256 + threadIdx.x;
    if (idx < 458752) {                       // 4*128*128*7 conv weights
        int k = idx % 7;
        int t = idx / 7;
        int i = t % HH; t /= HH;
        int o = t % HH;
        int lay = t / HH;
        wkb[((lay * 7 + k) * HH + o) * HH + i] = f2bf(w[idx]);
    } else {
        int j = idx - 458752;
        if (j < 49152) {                      // stacked QKV weights
            int t = j >> 14, r = j & 16383;
            float v = (t == 0) ? Wq[r] * qs : (t == 1) ? Wk[r] : Wv[r];
            wqkvb[j] = f2bf(v);
        } else if (j < 49536) {               // stacked biases
            int jj = j - 49152;
            b3[jj] = (jj < 128) ? bq[jj] * qs : (jj < 256) ? bk[jj - 128] : bv[jj - 256];
        } else if (j < 65920) {               // FF weights
            int jj = j - 49536;
            wffb[jj] = f2bf(Wff[jj]);
        } else {                              // h0 = x + positional encoding
            int p = j - 65920;                // one float4 per thread, 262144 total
            if (p < 262144) {
                int g = p >> 5, c4 = (p & 31) << 2;
                float4 val = *(const float4*)&x[g * HH + c4];
                float fg = (float)g;
#pragma unroll
                for (int h = 0; h < 2; h++) {
                    int i0 = c4 + h * 2;      // even -> i0 == (i0 & ~1)
                    float e = (float)i0 / 128.f;
                    float ang = fg / powf(10000.f, e);
                    ((float*)&val)[h * 2]     += sinf(ang);
                    ((float*)&val)[h * 2 + 1] += cosf(ang);
                }
                *(float4*)&h0[g * HH + c4] = val;
            }
        }
    }
}

// ---------------------------------------------------------------------------
// MEGA-KERNEL: 4x(LN -> conv(K=7) -> residual) + LN -> QKV gemms.
// Reads precomputed h0 = x + PE. Block owns 16 core rows; stages 48 rows
// (halo 16 each side). Halo recompute: wrong region grows 3 rows/layer from
// the window edge -> core rows stay exact.
// LDS: sF 25344 B + sA 13824 B = 39168 B -> 4 blocks/CU (was 3 at 44.5 KB);
// sT aliased into sA rows 20.. (dead region during the QKV phase).
// ---------------------------------------------------------------------------
__global__ __launch_bounds__(256, 4) void conv4qkv_kernel(const float* __restrict__ h0,
                                                          const short* __restrict__ wkb,
                                                          const float* __restrict__ conv_b,
                                                          const short* __restrict__ wqkvb,
                                                          const float* __restrict__ b3,
                                                          float* __restrict__ hB,
                                                          short* __restrict__ qb,
                                                          short* __restrict__ kb,
                                                          short* __restrict__ vt) {
    __shared__ float sF[48][132];
    __shared__ short sA[54 * 128];    // swizzled; rows 0..2 and 51..53 zero guards
    short* sT = sA + 20 * 128;        // [4][32][17] shorts, alias (QKV phase only)
    int tid = threadIdx.x;
    int w = tid >> 6, lane = tid & 63;
    int l15 = lane & 15, quad = lane >> 4;
    int m0 = blockIdx.x * 16;
    int c0 = w * 32;

    // ---- stage rows m0-16 .. m0+31 from h0, zero OOB ----
    for (int idx = tid; idx < 48 * 32; idx += 256) {
        int r = idx >> 5, c4 = (idx & 31) << 2;
        int g = m0 - 16 + r;
        float4 val = make_float4(0.f, 0.f, 0.f, 0.f);
        if (g >= 0 && g < LL) val = *(const float4*)&h0[g * HH + c4];
        *(float4*)&sF[r][c4] = val;
    }
    // ---- zero sA guard rows {0,1,2,51,52,53} (all-zero rows: swizzle-invariant) ----
    for (int idx = tid; idx < 6 * 64; idx += 256) {
        int rr = idx >> 6, cc = idx & 63;
        int row = (rr < 3) ? rr : 48 + rr;
        ((unsigned*)sA)[row * 64 + cc] = 0u;
    }

    // ---- 4 conv layers entirely in LDS ----
    for (int lay = 0; lay < 4; lay++) {
        __syncthreads();
        // LN staged rows 0..47 -> sA[row+3] (zero if global row OOB)
#pragma unroll
        for (int rr = 0; rr < 3; rr++) {
            int row = rr * 16 + w * 4 + quad;
            short8v pk = ln_pack8(&sF[row][0], l15);
            int g = m0 - 16 + row;
            if (g < 0 || g >= LL) pk = (short8v)(short)0;
            *(short8v*)sAp(sA, row + 3, l15 * 8) = pk;
        }
        __syncthreads();
        // conv via MFMA: 3 m-tiles x 2 n-tiles per wave, weights shared across mt
        f32x4 acc[3][2];
#pragma unroll
        for (int mt = 0; mt < 3; mt++) { acc[mt][0] = (f32x4)(0.f); acc[mt][1] = (f32x4)(0.f); }
        const short* wl = wkb + lay * 7 * HH * HH;
        for (int k = 0; k < 7; k++) {
            const short* b0 = wl + (k * HH + c0 + l15) * HH;
            const short* b1 = b0 + 16 * HH;
#pragma unroll
            for (int ks = 0; ks < 4; ks++) {
                short8v bf0 = *(const short8v*)&b0[ks * 32 + quad * 8];
                short8v bf1 = *(const short8v*)&b1[ks * 32 + quad * 8];
#pragma unroll
                for (int mt = 0; mt < 3; mt++) {
                    short8v af = *(const short8v*)sAp(sA, mt * 16 + l15 + k, ks * 32 + quad * 8);
                    acc[mt][0] = __builtin_amdgcn_mfma_f32_16x16x32_bf16(af, bf0, acc[mt][0], 0, 0, 0);
                    acc[mt][1] = __builtin_amdgcn_mfma_f32_16x16x32_bf16(af, bf1, acc[mt][1], 0, 0, 0);
                }
            }
        }
        float bb0 = conv_b[lay * HH + c0 + l15], bb1 = conv_b[lay * HH + c0 + 16 + l15];
#pragma unroll
        for (int mt = 0; mt < 3; mt++)
#pragma unroll
            for (int r = 0; r < 4; r++) {
                int row = mt * 16 + quad * 4 + r;
                sF[row][c0 + l15]      += acc[mt][0][r] + bb0;
                sF[row][c0 + 16 + l15] += acc[mt][1][r] + bb1;
            }
    }
    __syncthreads();
    // ---- write conv-stack output (core rows) ----
    for (int idx = tid; idx < 16 * 32; idx += 256) {
        int r = idx >> 5, c4 = (idx & 31) << 2;
        *(float4*)&hB[(m0 + r) * HH + c4] = *(const float4*)&sF[16 + r][c4];
    }
    // ---- LN core rows -> sA[0..15] ----
    {
        int row = w * 4 + quad;
        *(short8v*)sAp(sA, row, l15 * 8) = ln_pack8(&sF[16 + row][0], l15);
    }
    __syncthreads();
    // ---- QKV gemms ----
    short8v af4[4];
#pragma unroll
    for (int ks = 0; ks < 4; ks++)
        af4[ks] = *(const short8v*)sAp(sA, l15, ks * 32 + quad * 8);

    for (int t = 0; t < 3; t++) {
        f32x4 acc0 = (f32x4)(0.f), acc1 = (f32x4)(0.f);
        const short* b0 = wqkvb + (t * 128 + c0 + l15) * HH;
        const short* b1 = b0 + 16 * HH;
#pragma unroll
        for (int ks = 0; ks < 4; ks++) {
            short8v bf0 = *(const short8v*)&b0[ks * 32 + quad * 8];
            short8v bf1 = *(const short8v*)&b1[ks * 32 + quad * 8];
            acc0 = __builtin_amdgcn_mfma_f32_16x16x32_bf16(af4[ks], bf0, acc0, 0, 0, 0);
            acc1 = __builtin_amdgcn_mfma_f32_16x16x32_bf16(af4[ks], bf1, acc1, 0, 0, 0);
        }
        float bb0 = b3[t * 128 + c0 + l15], bb1 = b3[t * 128 + c0 + 16 + l15];
        if (t < 2) {
            short* o = (t == 0) ? qb : kb;
#pragma unroll
            for (int r = 0; r < 4; r++) {
                int lr = m0 + quad * 4 + r;
                o[lr * HH + c0 + l15]      = f2bf(acc0[r] + bb0);
                o[lr * HH + c0 + 16 + l15] = f2bf(acc1[r] + bb1);
            }
        } else {
#pragma unroll
            for (int r = 0; r < 4; r++) {
                sT[(w * 32 + l15) * 17 + quad * 4 + r]      = f2bf(acc0[r] + bb0);
                sT[(w * 32 + 16 + l15) * 17 + quad * 4 + r] = f2bf(acc1[r] + bb1);
            }
            asm volatile("s_waitcnt lgkmcnt(0)" ::: "memory");
#pragma unroll
            for (int cc = 0; cc < 8; cc++) {
                int col = cc * 4 + quad;
                vt[(c0 + col) * LL + m0 + l15] = sT[(w * 32 + col) * 17 + l15];
            }
        }
    }
}

// ---------------------------------------------------------------------------
// bf16 MFMA flash attention: 128 q-rows/block (4 waves x 32), KV chunk (64
// rows) staged per block into LDS in fragment-major order, register prefetch.
// KV split nsplit-way across blockIdx.y. No-max softmax, bf16 partials out.
// ---------------------------------------------------------------------------
#define FBN 64

__global__ __launch_bounds__(256, 2) void flash_mfma_kernel(const short* __restrict__ qs,
                                                            const short* __restrict__ ksrc,
                                                            const short* __restrict__ vsrc,
                                                            short* __restrict__ PO,
                                                            float* __restrict__ Pl,
                                                            int segrows) {
    __shared__ short sK[16 * 64 * 8];   // fragment-major, 16 KB
    __shared__ short sV[16 * 64 * 8];
    __shared__ short sP[4][32][72];     // per-wave P tiles

    const int tid = threadIdx.x;
    const int w = tid >> 6, lane = tid & 63;
    const int l15 = lane & 15, quad = lane >> 4;
    const int m0 = blockIdx.x * 128;
    const int seg = blockIdx.y;
    const int jbeg = seg * segrows;
    const int nchunk = segrows >> 6;

    const int vdt_base = (w >> 1);
    const int vks2 = w & 1;

    short8v qf[2][4];
#pragma unroll
    for (int mt = 0; mt < 2; mt++)
#pragma unroll
        for (int ks = 0; ks < 4; ks++)
            qf[mt][ks] = *(const short8v*)&qs[(m0 + w * 32 + mt * 16 + l15) * HH + ks * 32 + quad * 8];

    float l_r[2][4] = {{0.f, 0.f, 0.f, 0.f}, {0.f, 0.f, 0.f, 0.f}};
    f32x4 o_acc[2][8];
#pragma unroll
    for (int mt = 0; mt < 2; mt++)
#pragma unroll
        for (int dt = 0; dt < 8; dt++) o_acc[mt][dt] = (f32x4)(0.f);

    short8v kr[4], vr[4];
#pragma unroll
    for (int r = 0; r < 4; r++) {
        kr[r] = *(const short8v*)&ksrc[(jbeg + r * 16 + l15) * HH + w * 32 + quad * 8];
        vr[r] = *(const short8v*)&vsrc[((2 * r + vdt_base) * 16 + l15) * LL + jbeg + vks2 * 32 + quad * 8];
    }

    for (int c = 0; c < nchunk; c++) {
        __syncthreads();
#pragma unroll
        for (int r = 0; r < 4; r++) {
            *(short8v*)&sK[((w + 4 * r) * 64 + lane) * 8] = kr[r];
            *(short8v*)&sV[((w + 4 * r) * 64 + lane) * 8] = vr[r];
        }
        __syncthreads();
        if (c + 1 < nchunk) {
            const int j1 = jbeg + (c + 1) * FBN;
#pragma unroll
            for (int r = 0; r < 4; r++) {
                kr[r] = *(const short8v*)&ksrc[(j1 + r * 16 + l15) * HH + w * 32 + quad * 8];
                vr[r] = *(const short8v*)&vsrc[((2 * r + vdt_base) * 16 + l15) * LL + j1 + vks2 * 32 + quad * 8];
            }
        }
        // ---- S = Q K^T ----
        f32x4 s_acc[2][4];
#pragma unroll
        for (int mt = 0; mt < 2; mt++)
#pragma unroll
            for (int nt = 0; nt < 4; nt++) s_acc[mt][nt] = (f32x4)(0.f);
#pragma unroll
        for (int nt = 0; nt < 4; nt++)
#pragma unroll
            for (int ks = 0; ks < 4; ks++) {
                short8v kf = *(const short8v*)&sK[((nt * 4 + ks) * 64 + lane) * 8];
                s_acc[0][nt] = __builtin_amdgcn_mfma_f32_16x16x32_bf16(qf[0][ks], kf, s_acc[0][nt], 0, 0, 0);
                s_acc[1][nt] = __builtin_amdgcn_mfma_f32_16x16x32_bf16(qf[1][ks], kf, s_acc[1][nt], 0, 0, 0);
            }
        // ---- p = exp(s); per-lane row-sums; truncating bf16 pack to LDS ----
#pragma unroll
        for (int mt = 0; mt < 2; mt++)
#pragma unroll
            for (int nt = 0; nt < 4; nt++)
#pragma unroll
                for (int r = 0; r < 4; r++) {
                    float p = __expf(fminf(s_acc[mt][nt][r], 30.f));
                    l_r[mt][r] += p;
                    union { float f; unsigned u; } cv; cv.f = p;
                    sP[w][mt * 16 + quad * 4 + r][nt * 16 + l15] = (short)(cv.u >> 16);
                }
        asm volatile("s_waitcnt lgkmcnt(0)" ::: "memory");
        // ---- O += P V ----
#pragma unroll
        for (int ks2 = 0; ks2 < 2; ks2++) {
            short8v pf0 = *(const short8v*)&sP[w][l15][ks2 * 32 + quad * 8];
            short8v pf1 = *(const short8v*)&sP[w][16 + l15][ks2 * 32 + quad * 8];
#pragma unroll
            for (int dt = 0; dt < 8; dt++) {
                short8v vf = *(const short8v*)&sV[((dt * 2 + ks2) * 64 + lane) * 8];
                o_acc[0][dt] = __builtin_amdgcn_mfma_f32_16x16x32_bf16(pf0, vf, o_acc[0][dt], 0, 0, 0);
                o_acc[1][dt] = __builtin_amdgcn_mfma_f32_16x16x32_bf16(pf1, vf, o_acc[1][dt], 0, 0, 0);
            }
        }
    }
    // ---- finalize l, write partials ----
#pragma unroll
    for (int mt = 0; mt < 2; mt++)
#pragma unroll
        for (int r = 0; r < 4; r++) {
            float v = l_r[mt][r];
            v += __shfl_xor(v, 1, 64);
            v += __shfl_xor(v, 2, 64);
            v += __shfl_xor(v, 4, 64);
            v += __shfl_xor(v, 8, 64);
            if (l15 == 0)
                Pl[seg * LL + m0 + w * 32 + mt * 16 + quad * 4 + r] = v;
        }
#pragma unroll
    for (int mt = 0; mt < 2; mt++)
#pragma unroll
        for (int dt = 0; dt < 8; dt++)
#pragma unroll
            for (int r = 0; r < 4; r++)
                PO[(size_t)seg * LL * HH + (m0 + w * 32 + mt * 16 + quad * 4 + r) * HH + dt * 16 + l15] =
                    f2bf(o_acc[mt][dt][r]);
}

// ---------------------------------------------------------------------------
// fused attention-merge + residual + LN + FF gemm + relu + residual -> out
// ---------------------------------------------------------------------------
__global__ __launch_bounds__(256) void ff_kernel(const float* __restrict__ hin,
                                                 const short* __restrict__ PO,
                                                 const float* __restrict__ Pl,
                                                 const short* __restrict__ wffb,
                                                 const float* __restrict__ bff,
                                                 float* __restrict__ out,
                                                 int nsplit) {
    __shared__ float sF[16][132];
    __shared__ short sA[16 * 128];
    __shared__ float sLi[16];
    int tid = threadIdx.x;
    int w = tid >> 6, lane = tid & 63;
    int l15 = lane & 15, quad = lane >> 4;
    int m0 = blockIdx.x * 16;

    if (tid < 16) {
        float s = 0.f;
        for (int seg = 0; seg < nsplit; seg++) s += Pl[seg * LL + m0 + tid];
        sLi[tid] = 1.f / s;
    }
    __syncthreads();
    for (int idx = tid; idx < 16 * 32; idx += 256) {
        int r = idx >> 5, c4 = (idx & 31) << 2;
        float4 hv = *(const float4*)&hin[(m0 + r) * HH + c4];
        float s0 = 0.f, s1 = 0.f, s2 = 0.f, s3 = 0.f;
        for (int seg = 0; seg < nsplit; seg++) {
            short4v pv = *(const short4v*)&PO[(size_t)seg * LL * HH + (m0 + r) * HH + c4];
            s0 += bf2f(pv[0]); s1 += bf2f(pv[1]); s2 += bf2f(pv[2]); s3 += bf2f(pv[3]);
        }
        float li = sLi[r];
        *(float4*)&sF[r][c4] = make_float4(hv.x + s0 * li, hv.y + s1 * li,
                                           hv.z + s2 * li, hv.w + s3 * li);
    }
    __syncthreads();
    {
        int row = w * 4 + quad;
        *(short8v*)sAp(sA, row, l15 * 8) = ln_pack8(&sF[row][0], l15);
    }
    __syncthreads();
    int c0 = w * 32;
    f32x4 acc0 = (f32x4)(0.f), acc1 = (f32x4)(0.f);
    const short* b0 = wffb + (c0 + l15) * HH;
    const short* b1 = b0 + 16 * HH;
#pragma unroll
    for (int ks = 0; ks < 4; ks++) {
        short8v af = *(const short8v*)sAp(sA, l15, ks * 32 + quad * 8);
        short8v bf0 = *(const short8v*)&b0[ks * 32 + quad * 8];
        short8v bf1 = *(const short8v*)&b1[ks * 32 + quad * 8];
        acc0 = __builtin_amdgcn_mfma_f32_16x16x32_bf16(af, bf0, acc0, 0, 0, 0);
        acc1 = __builtin_amdgcn_mfma_f32_16x16x32_bf16(af, bf1, acc1, 0, 0, 0);
    }
    float bb0 = bff[c0 + l15], bb1 = bff[c0 + 16 + l15];
#pragma unroll
    for (int r = 0; r < 4; r++) {
        int lr = quad * 4 + r;
        out[(m0 + lr) * HH + c0 + l15]      = fmaxf(acc0[r] + bb0, 0.f) + sF[lr][c0 + l15];
        out[(m0 + lr) * HH + c0 + 16 + l15] = fmaxf(acc1[r] + bb1, 0.f) + sF[lr][c0 + 16 + l15];
    }
}

// ---------------------------------------------------------------------------
extern "C" void kernel_launch(void* const* d_in, const int* in_sizes, int n_in,
                              void* d_out, int out_size, void* d_ws, size_t ws_size,
                              hipStream_t stream) {
    const float* x      = (const float*)d_in[0];
    const float* conv_w = (const float*)d_in[1];
    const float* conv_b = (const float*)d_in[2];
    const float* Wq = (const float*)d_in[3];
    const float* bq = (const float*)d_in[4];
    const float* Wk = (const float*)d_in[5];
    const float* bk = (const float*)d_in[6];
    const float* Wv = (const float*)d_in[7];
    const float* bv = (const float*)d_in[8];
    const float* Wff = (const float*)d_in[9];
    const float* bff = (const float*)d_in[10];
    float* out = (float*)d_out;

    char* ws = (char*)d_ws;
    const size_t MB = 1u << 20;
    float* hB   = (float*)(ws);                              // 4 MB (residual, to end)
    short* qb   = (short*)(ws + 4 * MB);                     // 2 MB
    short* kb   = (short*)(ws + 6 * MB);                     // 2 MB
    short* vt   = (short*)(ws + 8 * MB);                     // 2 MB
    float* Pl   = (float*)(ws + 10 * MB);                    // <=512 KB
    short* wffb = (short*)(ws + 10 * MB + 524288);           // 32 KB
    short* PO   = (short*)(ws + 10 * MB + 524288 + 32768);   // 16 or 32 MB bf16
    // pre-flash-only buffers, aliased inside the PO span (dead before flash):
    short* wkb   = (short*)(ws + 16 * MB);                   // 896 KB
    short* wqkvb = (short*)(ws + 17 * MB);                   // 96 KB
    float* b3    = (float*)(ws + 17 * MB + 131072);          // 1.5 KB
    float* h0    = (float*)(ws + 18 * MB);                   // 4 MB (x + PE, dead before flash)

    // PO needs nsplit*2MB after its offset; pick split by available workspace.
    int nsplit = (ws_size >= (size_t)44 * MB) ? 16 : 8;
    int segrows = LL / nsplit;

    repack_all<<<3074, 256, 0, stream>>>(x, conv_w, Wq, Wk, Wv, bq, bk, bv, Wff,
                                         wkb, wqkvb, b3, wffb, h0);
    conv4qkv_kernel<<<LL / 16, 256, 0, stream>>>(h0, wkb, conv_b, wqkvb, b3,
                                                 hB, qb, kb, vt);
    flash_mfma_kernel<<<dim3(LL / 128, nsplit), 256, 0, stream>>>(qb, kb, vt, PO, Pl, segrows);
    ff_kernel<<<LL / 16, 256, 0, stream>>>(hB, PO, Pl, wffb, bff, out, nsplit);
}